// Round 23
// baseline (506.731 us; speedup 1.0000x reference)
//
#include <hip/hip_runtime.h>
#include <hip/hip_bf16.h>
#include <math.h>

// ---------------- constants ----------------
constexpr int Bc = 2, Sc = 2048, Dc = 512, Lc = 4, Vc = 32000;
constexpr int Mc = Bc * Sc;          // 4096 rows
constexpr int NSEG = 64;             // segments per sequence
constexpr int SEG = Sc / NSEG;       // 32 s per segment
constexpr float LN_EPS = 1e-5f;

typedef __attribute__((ext_vector_type(8))) short short8;   // 8 bf16
typedef __attribute__((ext_vector_type(4))) float f32x4;
typedef __attribute__((ext_vector_type(2))) float f32x2;

// ---------------- helpers ----------------
__device__ __forceinline__ void gload_lds16(const __hip_bfloat16* g, __hip_bfloat16* l) {
    __builtin_amdgcn_global_load_lds((const __attribute__((address_space(1))) void*)g,
                                     (__attribute__((address_space(3))) void*)l, 16, 0, 0);
}

// ---------------- fused prep: embed+PE+LN0  +  all weight transposes + bias pack ----------------
__global__ __launch_bounds__(256) void prep_all(const int* __restrict__ tokens,
                                                const float* __restrict__ emb,
                                                const float* __restrict__ ln_w0,
                                                const float* __restrict__ ln_b0,
                                                float* __restrict__ x,
                                                __hip_bfloat16* __restrict__ h16,
                                                const float* __restrict__ Wo,
                                                const float* __restrict__ Wm,
                                                const float* __restrict__ Wout,
                                                const float* __restrict__ Whead,
                                                const float* __restrict__ bo,
                                                const float* __restrict__ bm,
                                                __hip_bfloat16* __restrict__ Tommag,
                                                __hip_bfloat16* __restrict__ Tout,
                                                __hip_bfloat16* __restrict__ Thead,
                                                float* __restrict__ biasp) {
    int bid = blockIdx.x;
    int tx = threadIdx.x, ty = threadIdx.y;      // (32, 8)
    int t = ty * 32 + tx;                        // flat 0..255
    if (bid < 4096) {                            // ---- embed + PE + LN0 ----
        __shared__ float red[8];
        int row = bid;
        int s = row % Sc;
        int tok = tokens[row];
        const float kc = -9.210340371976184f / (float)Dc;   // -ln(10000)/D
        float div = expf((float)(2 * t) * kc);
        float ang = (float)s * div;
        const float* e = emb + (size_t)tok * Dc;
        float v0 = e[2 * t]     + sinf(ang);
        float v1 = e[2 * t + 1] + cosf(ang);
        float2 xv; xv.x = v0; xv.y = v1;
        ((float2*)x)[(size_t)row * (Dc / 2) + t] = xv;
        float sum = v0 + v1;
        for (int o = 32; o; o >>= 1) sum += __shfl_down(sum, o);
        if ((t & 63) == 0) red[t >> 6] = sum;
        __syncthreads();
        float mu = (red[0] + red[1] + red[2] + red[3]) * (1.f / (float)Dc);
        float d0 = v0 - mu, d1 = v1 - mu;
        float vs = d0 * d0 + d1 * d1;
        for (int o = 32; o; o >>= 1) vs += __shfl_down(vs, o);
        if ((t & 63) == 0) red[4 + (t >> 6)] = vs;
        __syncthreads();
        float var = (red[4] + red[5] + red[6] + red[7]) * (1.f / (float)Dc);
        float rstd = 1.f / sqrtf(var + LN_EPS);
        __hip_bfloat162 hb;
        hb.x = __float2bfloat16(d0 * rstd * ln_w0[2 * t] + ln_b0[2 * t]);
        hb.y = __float2bfloat16(d1 * rstd * ln_w0[2 * t + 1] + ln_b0[2 * t + 1]);
        ((__hip_bfloat162*)h16)[(size_t)row * (Dc / 2) + t] = hb;
        return;
    }
    bid -= 4096;
    if (bid >= 22144) {                          // ---- bias pack ----
        int l = bid - 22144;
        #pragma unroll
        for (int q = 0; q < 4; ++q) {
            int i = q * 256 + t;
            biasp[l * 1024 + i] = (i < 512) ? bo[l * 512 + i] : bm[l * 512 + i - 512];
        }
        return;
    }
    const float* ip;
    __hip_bfloat16* op;
    int C, LD, r0, c0;
    if (bid < 1024) {                            // W_omega
        int l = bid >> 8, rem = bid & 255;
        ip = Wo + (size_t)l * Dc * Dc;
        op = Tommag + (size_t)l * 1024 * Dc;
        C = Dc; LD = Dc;
        r0 = (rem >> 4) * 32; c0 = (rem & 15) * 32;
    } else if (bid < 2048) {                     // W_mag -> +512 row offset
        int b2 = bid - 1024;
        int l = b2 >> 8, rem = b2 & 255;
        ip = Wm + (size_t)l * Dc * Dc;
        op = Tommag + (size_t)l * 1024 * Dc + (size_t)512 * Dc;
        C = Dc; LD = Dc;
        r0 = (rem >> 4) * 32; c0 = (rem & 15) * 32;
    } else if (bid < 6144) {                     // W_out [2048][512]
        int b2 = bid - 2048;
        int l = b2 >> 10, rem = b2 & 1023;
        ip = Wout + (size_t)l * 4 * Dc * Dc;
        op = Tout + (size_t)l * Dc * 4 * Dc;
        C = Dc; LD = 4 * Dc;
        r0 = (rem >> 4) * 32; c0 = (rem & 15) * 32;
    } else {                                     // W_head [512][32000]
        int b2 = bid - 6144;
        ip = Whead;
        op = Thead;
        C = Vc; LD = Dc;
        r0 = (b2 / 1000) * 32; c0 = (b2 % 1000) * 32;
    }
    __shared__ float tile[32][33];
    #pragma unroll
    for (int q = 0; q < 4; ++q) {
        int r = r0 + ty + q * 8;
        tile[ty + q * 8][tx] = ip[(size_t)r * C + c0 + tx];
    }
    __syncthreads();
    #pragma unroll
    for (int q = 0; q < 4; ++q) {
        int c = c0 + ty + q * 8;
        op[(size_t)c * LD + r0 + tx] = __float2bfloat16(tile[tx][ty + q * 8]);
    }
}

// ---------------- split-K reduce + residual + LN(next), block = row ----------------
__global__ __launch_bounds__(256) void reduce_ln(const float* __restrict__ part,
                                                 const float* __restrict__ bout,
                                                 float* __restrict__ x,
                                                 const __hip_bfloat16* __restrict__ hres,
                                                 const float* __restrict__ w,
                                                 const float* __restrict__ bb,
                                                 __hip_bfloat16* __restrict__ hout,
                                                 int writeX) {
    __shared__ float red[8];
    int row = blockIdx.x;
    int t = threadIdx.x;
    const size_t MN = (size_t)Mc * Dc;
    size_t o2 = (size_t)row * (Dc / 2) + t;
    f32x2 p0 = __builtin_nontemporal_load((const f32x2*)part + o2);
    f32x2 p1 = __builtin_nontemporal_load((const f32x2*)part + MN / 2 + o2);
    f32x2 p2 = __builtin_nontemporal_load((const f32x2*)part + MN + o2);
    f32x2 p3 = __builtin_nontemporal_load((const f32x2*)part + 3 * (MN / 2) + o2);
    float2 xv = ((const float2*)x)[o2];
    __hip_bfloat162 hb = ((const __hip_bfloat162*)hres)[o2];
    float b0 = bout[2 * t], b1 = bout[2 * t + 1];
    float v0 = xv.x + p0[0] + p1[0] + p2[0] + p3[0] + b0 + __bfloat162float(hb.x);
    float v1 = xv.y + p0[1] + p1[1] + p2[1] + p3[1] + b1 + __bfloat162float(hb.y);
    if (writeX) {
        float2 nv; nv.x = v0; nv.y = v1;
        ((float2*)x)[o2] = nv;
    }
    // LN
    float sum = v0 + v1;
    for (int o = 32; o; o >>= 1) sum += __shfl_down(sum, o);
    if ((t & 63) == 0) red[t >> 6] = sum;
    __syncthreads();
    float mu = (red[0] + red[1] + red[2] + red[3]) * (1.f / (float)Dc);
    float d0 = v0 - mu, d1 = v1 - mu;
    float vs = d0 * d0 + d1 * d1;
    for (int o = 32; o; o >>= 1) vs += __shfl_down(vs, o);
    if ((t & 63) == 0) red[4 + (t >> 6)] = vs;
    __syncthreads();
    float var = (red[4] + red[5] + red[6] + red[7]) * (1.f / (float)Dc);
    float rstd = 1.f / sqrtf(var + LN_EPS);
    __hip_bfloat162 ho;
    ho.x = __float2bfloat16(d0 * rstd * w[2 * t] + bb[2 * t]);
    ho.y = __float2bfloat16(d1 * rstd * w[2 * t + 1] + bb[2 * t + 1]);
    ((__hip_bfloat162*)hout)[o2] = ho;
}

// ---------------- bf16 MFMA GEMM, BK=64, T2-swizzled LDS (layer GEMMs) ----------------
// EPI 0: Cf = acc + bias
// EPI 2: Cb = bf16(acc + bias)             (ommag output)
// EPI 3: Cf[z*M*N + .] = acc               (split-K partial, no bias; NONTEMPORAL — read once)
template<int BM, int EPI, int SPLITK = 1>
__global__ __launch_bounds__(256) void gemm_bt(const __hip_bfloat16* __restrict__ A,
                                               const __hip_bfloat16* __restrict__ Bt,
                                               const float* __restrict__ bias,
                                               float* __restrict__ Cf,
                                               __hip_bfloat16* __restrict__ Cb,
                                               int M, int N, int K) {
    __shared__ __hip_bfloat16 As[BM * 64];
    __shared__ __hip_bfloat16 Bs[128 * 64];
    const int tid = threadIdx.x;
    const int lane = tid & 63;
    const int wave = tid >> 6;
    const int wr = wave >> 1, wc = wave & 1;
    int nwg = gridDim.x * gridDim.y;
    int flat = blockIdx.y * gridDim.x + blockIdx.x;
    int cpx = nwg >> 3;
    int swz = (flat & 7) * cpx + (flat >> 3);
    const int m0 = (swz / gridDim.x) * BM;
    const int n0 = (swz % gridDim.x) * 128;
    const int zz = (SPLITK > 1) ? blockIdx.z : 0;
    const int kbeg = zz * (K / SPLITK);
    const int kend = kbeg + K / SPLITK;
    const int fr = lane & 15, fq = lane >> 4;
    constexpr int MI = BM / 32;
    f32x4 acc[MI][4] = {};
    for (int k0 = kbeg; k0 < kend; k0 += 64) {
        #pragma unroll
        for (int q = 0; q < BM / 32; ++q) {
            int c = q * 256 + tid;
            int row = c >> 3, cb = c & 7;
            int gcb = cb ^ (row & 7);
            gload_lds16(A + (size_t)(m0 + row) * K + (k0 + gcb * 8), &As[c * 8]);
        }
        #pragma unroll
        for (int q = 0; q < 4; ++q) {
            int c = q * 256 + tid;
            int row = c >> 3, cb = c & 7;
            int gcb = cb ^ (row & 7);
            gload_lds16(Bt + (size_t)(n0 + row) * K + (k0 + gcb * 8), &Bs[c * 8]);
        }
        __syncthreads();
        #pragma unroll
        for (int ks = 0; ks < 2; ++ks) {
            short8 a[MI], b[4];
            #pragma unroll
            for (int i = 0; i < MI; ++i) {
                int row = wr * (BM / 2) + i * 16 + fr;
                int sb = (ks * 4 + fq) ^ (row & 7);
                a[i] = *(const short8*)&As[row * 64 + sb * 8];
            }
            #pragma unroll
            for (int j = 0; j < 4; ++j) {
                int row = wc * 64 + j * 16 + fr;
                int sb = (ks * 4 + fq) ^ (row & 7);
                b[j] = *(const short8*)&Bs[row * 64 + sb * 8];
            }
            #pragma unroll
            for (int i = 0; i < MI; ++i)
                #pragma unroll
                for (int j = 0; j < 4; ++j)
                    acc[i][j] = __builtin_amdgcn_mfma_f32_16x16x32_bf16(a[i], b[j], acc[i][j], 0, 0, 0);
        }
        __syncthreads();
    }
    float* Cfz = Cf + (size_t)zz * M * N;
    #pragma unroll
    for (int i = 0; i < MI; ++i) {
        int rowb = m0 + wr * (BM / 2) + i * 16 + fq * 4;
        #pragma unroll
        for (int j = 0; j < 4; ++j) {
            int col = n0 + wc * 64 + j * 16 + fr;
            float bv = (EPI == 3) ? 0.f : bias[col];
            #pragma unroll
            for (int t = 0; t < 4; ++t) {
                size_t idx = (size_t)(rowb + t) * N + col;
                float v = acc[i][j][t] + bv;
                if constexpr (EPI == 0) Cf[idx] = v;
                else if constexpr (EPI == 2) Cb[idx] = __float2bfloat16(v);
                else __builtin_nontemporal_store(v, &Cfz[idx]);
            }
        }
    }
}

// ---------------- head GEMM: n-stripe persistent-B + transposed epilogue + NT stores ----------------
// Block owns a 64-col n-stripe; B panel (64x512 = 64KB) staged once; 16 m-tiles (BM=128, BK=64).
// Grid (500,2) = 1000 blocks at 2 blocks/CU. Epilogue: rotation-swizzled wave-local LDS transpose
// -> 256B-contiguous f32x4 NONTEMPORAL stores (logits never re-read; keep them out of L2).
__global__ __launch_bounds__(256) void gemm_head_ns(const __hip_bfloat16* __restrict__ A,
                                                    const __hip_bfloat16* __restrict__ Bt,
                                                    const float* __restrict__ bias,
                                                    float* __restrict__ C,
                                                    int M, int N, int K) {
    __shared__ __hip_bfloat16 Bs[64 * 512];   // 64 KB persistent B panel
    __shared__ __hip_bfloat16 As[128 * 64];   // 16 KB A tile; reused as epilogue buffer
    const int tid = threadIdx.x;
    const int lane = tid & 63;
    const int wave = tid >> 6;                // 4 waves, each owns 32 rows x 64 cols
    const int n0 = blockIdx.x * 64;
    const int mbase = blockIdx.y * 2048;      // 16 m-tiles of 128
    const int fr = lane & 15, fq = lane >> 4;
    // stage B panel: slot c = (row, kc, cb); source colblk gcb = cb^(row&7)
    #pragma unroll
    for (int q = 0; q < 16; ++q) {
        int c = q * 256 + tid;
        int row = c >> 6, rem = c & 63;
        int kc = rem >> 3, cb = rem & 7;
        int gcb = cb ^ (row & 7);
        gload_lds16(Bt + (size_t)(n0 + row) * K + (kc * 64 + gcb * 8), &Bs[c * 8]);
    }
    // epilogue constants (per lane)
    float* ebuf = (float*)As + wave * 1024;   // 16 rows x 64 f32 per wave
    const int erow = lane >> 4;               // 0..3 (row group for reads)
    const int ecol = (lane & 15) * 4;         // col start (true col)
    f32x4 bias4 = *(const f32x4*)&bias[n0 + ecol];
    for (int mt = 0; mt < 16; ++mt) {
        const int m0 = mbase + mt * 128;
        f32x4 acc[2][4] = {};
        for (int kc = 0; kc < 8; ++kc) {
            if (kc == 0) __syncthreads();      // epilogue readers done before As overwrite
            #pragma unroll
            for (int q = 0; q < 4; ++q) {
                int c = q * 256 + tid;
                int row = c >> 3, cb = c & 7;
                int gcb = cb ^ (row & 7);
                gload_lds16(A + (size_t)(m0 + row) * K + (kc * 64 + gcb * 8), &As[c * 8]);
            }
            __syncthreads();   // drains staging (and B on first iter)
            #pragma unroll
            for (int ks = 0; ks < 2; ++ks) {
                short8 a[2], b[4];
                #pragma unroll
                for (int i = 0; i < 2; ++i) {
                    int row = wave * 32 + i * 16 + fr;
                    int sb = (ks * 4 + fq) ^ (row & 7);
                    a[i] = *(const short8*)&As[row * 64 + sb * 8];
                }
                #pragma unroll
                for (int j = 0; j < 4; ++j) {
                    int row = j * 16 + fr;
                    int sb = (ks * 4 + fq) ^ (row & 7);
                    b[j] = *(const short8*)&Bs[row * 512 + kc * 64 + sb * 8];
                }
                #pragma unroll
                for (int i = 0; i < 2; ++i)
                    #pragma unroll
                    for (int j = 0; j < 4; ++j)
                        acc[i][j] = __builtin_amdgcn_mfma_f32_16x16x32_bf16(a[i], b[j], acc[i][j], 0, 0, 0);
            }
            __syncthreads();   // protect As before next stage
        }
        // ---- wave-local transposed epilogue (no cross-wave sync needed) ----
        #pragma unroll
        for (int i = 0; i < 2; ++i) {
            // producer: scalar ds_write with rotation swizzle
            #pragma unroll
            for (int j = 0; j < 4; ++j)
                #pragma unroll
                for (int t = 0; t < 4; ++t) {
                    int row = fq * 4 + t;                       // 0..15 in-fragment
                    int col = j * 16 + fr;
                    ebuf[row * 64 + ((col + 4 * row) & 63)] = acc[i][j][t];
                }
            // consumer: 4 rows per pass, 256B contiguous nontemporal stores
            #pragma unroll
            for (int k = 0; k < 4; ++k) {
                int rowf = erow + 4 * k;                        // 0..15
                int colp = (ecol + 4 * rowf) & 63;
                f32x4 v = *(f32x4*)&ebuf[rowf * 64 + colp];
                f32x4 o = v + bias4;
                int grow = m0 + wave * 32 + i * 16 + rowf;
                __builtin_nontemporal_store(o, (f32x4*)&C[(size_t)grow * N + n0 + ecol]);
            }
        }
    }
}

// ---------------- scan pass 1: per-segment totals ----------------
// segTot layout: [B][NSEG][6][D]  (q: 0=P 1=cosP 2=sinP 3=Wc 4=Ws 5=Acc)
__global__ __launch_bounds__(256) void scan_pass1(const __hip_bfloat16* __restrict__ ommag,
                                                  const __hip_bfloat16* __restrict__ h16,
                                                  const float* __restrict__ iscale,
                                                  float* __restrict__ segTot) {
    int td = threadIdx.x;          // 0..63
    int ts = threadIdx.y;          // 0..3
    int d = blockIdx.x * 64 + td;
    int seg = blockIdx.y * 4 + ts;
    int b = blockIdx.z;
    size_t rbase = (size_t)b * Sc + seg * SEG;
    const __hip_bfloat16* om = ommag + rbase * 1024 + d;
    const __hip_bfloat16* mg = om + 512;
    const __hip_bfloat16* hp = h16 + rbase * Dc + d;
    float isc = fabsf(iscale[d]);
    float phi = 0.f, swc = 0.f, sws = 0.f, sacc = 0.f;
    for (int k = 0; k < SEG; ++k) {
        float o = __bfloat162float(om[(size_t)k * 1024]);
        float mp = __bfloat162float(mg[(size_t)k * 1024]);
        float hh = __bfloat162float(hp[(size_t)k * Dc]);
        phi += o * isc;
        float mag = 5.f / (1.f + __expf(-mp));
        float sn, cs; __sincosf(phi, &sn, &cs);
        float w = mag * hh;
        swc += w * cs; sws += w * sn; sacc += mag;
    }
    float cP, sP; __sincosf(phi, &sP, &cP);
    size_t o = (((size_t)b * NSEG + seg) * 6) * Dc + d;
    segTot[o] = phi; segTot[o + Dc] = cP; segTot[o + 2 * Dc] = sP;
    segTot[o + 3 * Dc] = swc; segTot[o + 4 * Dc] = sws; segTot[o + 5 * Dc] = sacc;
}

// ---------------- scan pass 3: quartered associative lookback + sweep, write ctx ----------------
__global__ __launch_bounds__(256) void scan_pass3(const __hip_bfloat16* __restrict__ ommag,
                                                  const __hip_bfloat16* __restrict__ h16,
                                                  const float* __restrict__ iscale,
                                                  const float* __restrict__ segTot,
                                                  __hip_bfloat16* __restrict__ ctx) {
    __shared__ float Q[4][6][64];   // per-quarter summary: P, zr, zi, Wr, Wi, A
    int td = threadIdx.x;
    int ts = threadIdx.y;
    int d = blockIdx.x * 64 + td;
    int jj = blockIdx.y;            // block covers segs 4jj..4jj+3
    int seg = jj * 4 + ts;
    int b = blockIdx.z;
    size_t rbase = (size_t)b * Sc + seg * SEG;
    const __hip_bfloat16* om = ommag + rbase * 1024 + d;
    const __hip_bfloat16* mg = om + 512;
    const __hip_bfloat16* hp = h16 + rbase * Dc + d;
    float isc = fabsf(iscale[d]);
    // phase A: quarter ts summarizes segments [ts*jj, (ts+1)*jj) in local frame
    {
        float Pq = 0.f, zr = 1.f, zi = 0.f, Wr = 0.f, Wi = 0.f, Aq = 0.f;
        for (int c = ts * jj; c < (ts + 1) * jj; ++c) {
            size_t o = (((size_t)b * NSEG + c) * 6) * Dc + d;
            float P = segTot[o], cp = segTot[o + Dc], sp = segTot[o + 2 * Dc];
            float wcv = segTot[o + 3 * Dc], wsv = segTot[o + 4 * Dc], acv = segTot[o + 5 * Dc];
            Wr += zr * wcv - zi * wsv;
            Wi += zi * wcv + zr * wsv;
            Aq += acv; Pq += P;
            float nzr = zr * cp - zi * sp;
            float nzi = zi * cp + zr * sp;
            zr = nzr; zi = nzi;
        }
        Q[ts][0][td] = Pq; Q[ts][1][td] = zr; Q[ts][2][td] = zi;
        Q[ts][3][td] = Wr; Q[ts][4][td] = Wi; Q[ts][5][td] = Aq;
    }
    __syncthreads();
    // phase B: compose quarters 0..3 (prefix [0,4jj)), then singles [4jj, 4jj+ts)
    float PHI = 0.f, UR = 0.f, UI = 0.f, AC = 0.f, gzr = 1.f, gzi = 0.f;
    #pragma unroll
    for (int q = 0; q < 4; ++q) {
        float wr = Q[q][3][td], wi = Q[q][4][td];
        UR += gzr * wr - gzi * wi;
        UI += gzi * wr + gzr * wi;
        AC += Q[q][5][td]; PHI += Q[q][0][td];
        float nzr = gzr * Q[q][1][td] - gzi * Q[q][2][td];
        float nzi = gzi * Q[q][1][td] + gzr * Q[q][2][td];
        gzr = nzr; gzi = nzi;
    }
    for (int c = 4 * jj; c < 4 * jj + ts; ++c) {
        size_t o = (((size_t)b * NSEG + c) * 6) * Dc + d;
        float P = segTot[o], cp = segTot[o + Dc], sp = segTot[o + 2 * Dc];
        float wcv = segTot[o + 3 * Dc], wsv = segTot[o + 4 * Dc], acv = segTot[o + 5 * Dc];
        UR += gzr * wcv - gzi * wsv;
        UI += gzi * wcv + gzr * wsv;
        AC += acv; PHI += P;
        float nzr = gzr * cp - gzi * sp;
        float nzi = gzi * cp + gzr * sp;
        gzr = nzr; gzi = nzi;
    }
    // phase C: sweep, write ctx
    float phi = PHI;
    __hip_bfloat16* ctxp = ctx + rbase * (4 * Dc) + d;
    for (int k = 0; k < SEG; ++k) {
        float o = __bfloat162float(om[(size_t)k * 1024]);
        float mp = __bfloat162float(mg[(size_t)k * 1024]);
        float hh = __bfloat162float(hp[(size_t)k * Dc]);
        phi += o * isc;
        float mag = 5.f / (1.f + __expf(-mp));
        float sn, cs; __sincosf(phi, &sn, &cs);
        float w = mag * hh;
        UR += w * cs; UI += w * sn; AC += mag;
        float inv = 1.f / (AC + 1e-8f);
        float mr = UR * inv, mi = UI * inv;
        float rr = mr * cs + mi * sn;
        float ri = mi * cs - mr * sn;
        size_t oo = (size_t)k * (4 * Dc);
        ctxp[oo]          = __float2bfloat16(hh * cs);
        ctxp[oo + Dc]     = __float2bfloat16(hh * sn);
        ctxp[oo + 2 * Dc] = __float2bfloat16(rr);
        ctxp[oo + 3 * Dc] = __float2bfloat16(ri);
    }
}

// ---------------- launch ----------------
extern "C" void kernel_launch(void* const* d_in, const int* in_sizes, int n_in,
                              void* d_out, int out_size, void* d_ws, size_t ws_size,
                              hipStream_t stream) {
    const int*   tokens    = (const int*)d_in[0];
    const float* emb       = (const float*)d_in[1];
    const float* ln_w      = (const float*)d_in[2];
    const float* ln_b      = (const float*)d_in[3];
    const float* W_omega   = (const float*)d_in[4];
    const float* b_omega   = (const float*)d_in[5];
    const float* int_scale = (const float*)d_in[6];
    const float* W_mag     = (const float*)d_in[7];
    const float* b_mag     = (const float*)d_in[8];
    const float* W_out     = (const float*)d_in[9];
    const float* b_out     = (const float*)d_in[10];
    const float* fln_w     = (const float*)d_in[11];
    const float* fln_b     = (const float*)d_in[12];
    const float* W_head    = (const float*)d_in[13];
    const float* b_head    = (const float*)d_in[14];
    float* out = (float*)d_out;

    char* ws = (char*)d_ws;
    size_t off = 0;
    auto alloc = [&](size_t bytes) -> char* {
        char* p = ws + off;
        off += (bytes + 255) / 256 * 256;
        return p;
    };
    const size_t MD = (size_t)Mc * Dc;
    float* x        = (float*)alloc(MD * 4);
    float* part     = (float*)alloc(MD * 4 * 4);                    // split-K partials [4][M][512]
    __hip_bfloat16* ommag16 = (__hip_bfloat16*)alloc(MD * 2 * 2);   // [M][1024] bf16
    __hip_bfloat16* h16    = (__hip_bfloat16*)alloc(MD * 2);
    __hip_bfloat16* ctx16  = (__hip_bfloat16*)alloc(MD * 4 * 2);
    __hip_bfloat16* xln16  = (__hip_bfloat16*)alloc(MD * 2);
    float* segTot   = (float*)alloc((size_t)Bc * NSEG * 6 * Dc * 4);
    __hip_bfloat16* Wt_ommag = (__hip_bfloat16*)alloc((size_t)Lc * 1024 * Dc * 2);
    __hip_bfloat16* Wt_out   = (__hip_bfloat16*)alloc((size_t)Lc * Dc * 4 * Dc * 2);
    __hip_bfloat16* Wt_head  = (__hip_bfloat16*)alloc((size_t)Vc * Dc * 2);
    float* bias_ommag        = (float*)alloc((size_t)Lc * 1024 * 4);

    // fused prep: embed+LN0 + all transposes + bias pack (26244 blocks)
    prep_all<<<26244, dim3(32, 8), 0, stream>>>(
        tokens, emb, ln_w, ln_b, x, h16,
        W_omega, W_mag, W_out, W_head, b_omega, b_mag,
        Wt_ommag, Wt_out, Wt_head, bias_ommag);

    dim3 scanGrid(Dc / 64, NSEG / 4, Bc);
    dim3 scanBlk(64, 4);
    for (int l = 0; l < Lc; ++l) {
        gemm_bt<128, 2><<<dim3(1024 / 128, Mc / 128), 256, 0, stream>>>(
            h16, Wt_ommag + (size_t)l * 1024 * Dc, bias_ommag + l * 1024, nullptr, ommag16, Mc, 1024, Dc);
        scan_pass1<<<scanGrid, scanBlk, 0, stream>>>(ommag16, h16, int_scale + l * Dc, segTot);
        scan_pass3<<<scanGrid, scanBlk, 0, stream>>>(ommag16, h16, int_scale + l * Dc, segTot, ctx16);
        gemm_bt<128, 3, 4><<<dim3(Dc / 128, Mc / 128, 4), 256, 0, stream>>>(
            ctx16, Wt_out + (size_t)l * Dc * 4 * Dc, nullptr, part, nullptr, Mc, Dc, 4 * Dc);
        const float* wsel = (l + 1 < Lc) ? (ln_w + (l + 1) * Dc) : fln_w;
        const float* bsel = (l + 1 < Lc) ? (ln_b + (l + 1) * Dc) : fln_b;
        __hip_bfloat16* hsel = (l + 1 < Lc) ? h16 : xln16;
        reduce_ln<<<Mc, 256, 0, stream>>>(part, b_out + l * Dc, x, h16, wsel, bsel, hsel,
                                          (l + 1 < Lc) ? 1 : 0);
    }
    // head: n-stripe persistent-B, 16 m-tiles per block, NT logit stores
    gemm_head_ns<<<dim3(Vc / 64, Mc / 2048), 256, 0, stream>>>(
        xln16, Wt_head, b_head, out, Mc, Vc, Dc);
}

// Round 24
// 491.256 us; speedup vs baseline: 1.0315x; 1.0315x over previous
//
#include <hip/hip_runtime.h>
#include <hip/hip_bf16.h>
#include <math.h>

// ---------------- constants ----------------
constexpr int Bc = 2, Sc = 2048, Dc = 512, Lc = 4, Vc = 32000;
constexpr int Mc = Bc * Sc;          // 4096 rows
constexpr int NSEG = 64;             // segments per sequence
constexpr int SEG = Sc / NSEG;       // 32 s per segment
constexpr float LN_EPS = 1e-5f;

typedef __attribute__((ext_vector_type(8))) short short8;   // 8 bf16
typedef __attribute__((ext_vector_type(4))) float f32x4;

// ---------------- helpers ----------------
__device__ __forceinline__ void gload_lds16(const __hip_bfloat16* g, __hip_bfloat16* l) {
    __builtin_amdgcn_global_load_lds((const __attribute__((address_space(1))) void*)g,
                                     (__attribute__((address_space(3))) void*)l, 16, 0, 0);
}

// ---------------- fused prep: embed+PE+LN0  +  all weight transposes + bias pack ----------------
__global__ __launch_bounds__(256) void prep_all(const int* __restrict__ tokens,
                                                const float* __restrict__ emb,
                                                const float* __restrict__ ln_w0,
                                                const float* __restrict__ ln_b0,
                                                float* __restrict__ x,
                                                __hip_bfloat16* __restrict__ h16,
                                                const float* __restrict__ Wo,
                                                const float* __restrict__ Wm,
                                                const float* __restrict__ Wout,
                                                const float* __restrict__ Whead,
                                                const float* __restrict__ bo,
                                                const float* __restrict__ bm,
                                                __hip_bfloat16* __restrict__ Tommag,
                                                __hip_bfloat16* __restrict__ Tout,
                                                __hip_bfloat16* __restrict__ Thead,
                                                float* __restrict__ biasp) {
    int bid = blockIdx.x;
    int tx = threadIdx.x, ty = threadIdx.y;      // (32, 8)
    int t = ty * 32 + tx;                        // flat 0..255
    if (bid < 4096) {                            // ---- embed + PE + LN0 ----
        __shared__ float red[8];
        int row = bid;
        int s = row % Sc;
        int tok = tokens[row];
        const float kc = -9.210340371976184f / (float)Dc;   // -ln(10000)/D
        float div = expf((float)(2 * t) * kc);
        float ang = (float)s * div;
        const float* e = emb + (size_t)tok * Dc;
        float v0 = e[2 * t]     + sinf(ang);
        float v1 = e[2 * t + 1] + cosf(ang);
        float2 xv; xv.x = v0; xv.y = v1;
        ((float2*)x)[(size_t)row * (Dc / 2) + t] = xv;
        float sum = v0 + v1;
        for (int o = 32; o; o >>= 1) sum += __shfl_down(sum, o);
        if ((t & 63) == 0) red[t >> 6] = sum;
        __syncthreads();
        float mu = (red[0] + red[1] + red[2] + red[3]) * (1.f / (float)Dc);
        float d0 = v0 - mu, d1 = v1 - mu;
        float vs = d0 * d0 + d1 * d1;
        for (int o = 32; o; o >>= 1) vs += __shfl_down(vs, o);
        if ((t & 63) == 0) red[4 + (t >> 6)] = vs;
        __syncthreads();
        float var = (red[4] + red[5] + red[6] + red[7]) * (1.f / (float)Dc);
        float rstd = 1.f / sqrtf(var + LN_EPS);
        __hip_bfloat162 hb;
        hb.x = __float2bfloat16(d0 * rstd * ln_w0[2 * t] + ln_b0[2 * t]);
        hb.y = __float2bfloat16(d1 * rstd * ln_w0[2 * t + 1] + ln_b0[2 * t + 1]);
        ((__hip_bfloat162*)h16)[(size_t)row * (Dc / 2) + t] = hb;
        return;
    }
    bid -= 4096;
    if (bid >= 22144) {                          // ---- bias pack ----
        int l = bid - 22144;
        #pragma unroll
        for (int q = 0; q < 4; ++q) {
            int i = q * 256 + t;
            biasp[l * 1024 + i] = (i < 512) ? bo[l * 512 + i] : bm[l * 512 + i - 512];
        }
        return;
    }
    const float* ip;
    __hip_bfloat16* op;
    int C, LD, r0, c0;
    if (bid < 1024) {                            // W_omega
        int l = bid >> 8, rem = bid & 255;
        ip = Wo + (size_t)l * Dc * Dc;
        op = Tommag + (size_t)l * 1024 * Dc;
        C = Dc; LD = Dc;
        r0 = (rem >> 4) * 32; c0 = (rem & 15) * 32;
    } else if (bid < 2048) {                     // W_mag -> +512 row offset
        int b2 = bid - 1024;
        int l = b2 >> 8, rem = b2 & 255;
        ip = Wm + (size_t)l * Dc * Dc;
        op = Tommag + (size_t)l * 1024 * Dc + (size_t)512 * Dc;
        C = Dc; LD = Dc;
        r0 = (rem >> 4) * 32; c0 = (rem & 15) * 32;
    } else if (bid < 6144) {                     // W_out [2048][512]
        int b2 = bid - 2048;
        int l = b2 >> 10, rem = b2 & 1023;
        ip = Wout + (size_t)l * 4 * Dc * Dc;
        op = Tout + (size_t)l * Dc * 4 * Dc;
        C = Dc; LD = 4 * Dc;
        r0 = (rem >> 4) * 32; c0 = (rem & 15) * 32;
    } else {                                     // W_head [512][32000]
        int b2 = bid - 6144;
        ip = Whead;
        op = Thead;
        C = Vc; LD = Dc;
        r0 = (b2 / 1000) * 32; c0 = (b2 % 1000) * 32;
    }
    __shared__ float tile[32][33];
    #pragma unroll
    for (int q = 0; q < 4; ++q) {
        int r = r0 + ty + q * 8;
        tile[ty + q * 8][tx] = ip[(size_t)r * C + c0 + tx];
    }
    __syncthreads();
    #pragma unroll
    for (int q = 0; q < 4; ++q) {
        int c = c0 + ty + q * 8;
        op[(size_t)c * LD + r0 + tx] = __float2bfloat16(tile[tx][ty + q * 8]);
    }
}

// ---------------- split-K reduce + residual + LN(next), block = row ----------------
__global__ __launch_bounds__(256) void reduce_ln(const float* __restrict__ part,
                                                 const float* __restrict__ bout,
                                                 float* __restrict__ x,
                                                 const __hip_bfloat16* __restrict__ hres,
                                                 const float* __restrict__ w,
                                                 const float* __restrict__ bb,
                                                 __hip_bfloat16* __restrict__ hout,
                                                 int writeX) {
    __shared__ float red[8];
    int row = blockIdx.x;
    int t = threadIdx.x;
    const size_t MN = (size_t)Mc * Dc;
    size_t o2 = (size_t)row * (Dc / 2) + t;
    float2 p0 = ((const float2*)part)[o2];
    float2 p1 = ((const float2*)part)[MN / 2 + o2];
    float2 p2 = ((const float2*)part)[MN + o2];
    float2 p3 = ((const float2*)part)[3 * (MN / 2) + o2];
    float2 xv = ((const float2*)x)[o2];
    __hip_bfloat162 hb = ((const __hip_bfloat162*)hres)[o2];
    float b0 = bout[2 * t], b1 = bout[2 * t + 1];
    float v0 = xv.x + p0.x + p1.x + p2.x + p3.x + b0 + __bfloat162float(hb.x);
    float v1 = xv.y + p0.y + p1.y + p2.y + p3.y + b1 + __bfloat162float(hb.y);
    if (writeX) {
        float2 nv; nv.x = v0; nv.y = v1;
        ((float2*)x)[o2] = nv;
    }
    // LN
    float sum = v0 + v1;
    for (int o = 32; o; o >>= 1) sum += __shfl_down(sum, o);
    if ((t & 63) == 0) red[t >> 6] = sum;
    __syncthreads();
    float mu = (red[0] + red[1] + red[2] + red[3]) * (1.f / (float)Dc);
    float d0 = v0 - mu, d1 = v1 - mu;
    float vs = d0 * d0 + d1 * d1;
    for (int o = 32; o; o >>= 1) vs += __shfl_down(vs, o);
    if ((t & 63) == 0) red[4 + (t >> 6)] = vs;
    __syncthreads();
    float var = (red[4] + red[5] + red[6] + red[7]) * (1.f / (float)Dc);
    float rstd = 1.f / sqrtf(var + LN_EPS);
    __hip_bfloat162 ho;
    ho.x = __float2bfloat16(d0 * rstd * w[2 * t] + bb[2 * t]);
    ho.y = __float2bfloat16(d1 * rstd * w[2 * t + 1] + bb[2 * t + 1]);
    ((__hip_bfloat162*)hout)[o2] = ho;
}

// ---------------- bf16 MFMA GEMM, BK=64, T2-swizzled LDS (layer GEMMs) ----------------
// EPI 0: Cf = acc + bias
// EPI 2: Cb = bf16(acc + bias)             (ommag output)
// EPI 3: Cf[z*M*N + .] = acc               (split-K partial, no bias)
template<int BM, int EPI, int SPLITK = 1>
__global__ __launch_bounds__(256) void gemm_bt(const __hip_bfloat16* __restrict__ A,
                                               const __hip_bfloat16* __restrict__ Bt,
                                               const float* __restrict__ bias,
                                               float* __restrict__ Cf,
                                               __hip_bfloat16* __restrict__ Cb,
                                               int M, int N, int K) {
    __shared__ __hip_bfloat16 As[BM * 64];
    __shared__ __hip_bfloat16 Bs[128 * 64];
    const int tid = threadIdx.x;
    const int lane = tid & 63;
    const int wave = tid >> 6;
    const int wr = wave >> 1, wc = wave & 1;
    int nwg = gridDim.x * gridDim.y;
    int flat = blockIdx.y * gridDim.x + blockIdx.x;
    int cpx = nwg >> 3;
    int swz = (flat & 7) * cpx + (flat >> 3);
    const int m0 = (swz / gridDim.x) * BM;
    const int n0 = (swz % gridDim.x) * 128;
    const int zz = (SPLITK > 1) ? blockIdx.z : 0;
    const int kbeg = zz * (K / SPLITK);
    const int kend = kbeg + K / SPLITK;
    const int fr = lane & 15, fq = lane >> 4;
    constexpr int MI = BM / 32;
    f32x4 acc[MI][4] = {};
    for (int k0 = kbeg; k0 < kend; k0 += 64) {
        #pragma unroll
        for (int q = 0; q < BM / 32; ++q) {
            int c = q * 256 + tid;
            int row = c >> 3, cb = c & 7;
            int gcb = cb ^ (row & 7);
            gload_lds16(A + (size_t)(m0 + row) * K + (k0 + gcb * 8), &As[c * 8]);
        }
        #pragma unroll
        for (int q = 0; q < 4; ++q) {
            int c = q * 256 + tid;
            int row = c >> 3, cb = c & 7;
            int gcb = cb ^ (row & 7);
            gload_lds16(Bt + (size_t)(n0 + row) * K + (k0 + gcb * 8), &Bs[c * 8]);
        }
        __syncthreads();
        #pragma unroll
        for (int ks = 0; ks < 2; ++ks) {
            short8 a[MI], b[4];
            #pragma unroll
            for (int i = 0; i < MI; ++i) {
                int row = wr * (BM / 2) + i * 16 + fr;
                int sb = (ks * 4 + fq) ^ (row & 7);
                a[i] = *(const short8*)&As[row * 64 + sb * 8];
            }
            #pragma unroll
            for (int j = 0; j < 4; ++j) {
                int row = wc * 64 + j * 16 + fr;
                int sb = (ks * 4 + fq) ^ (row & 7);
                b[j] = *(const short8*)&Bs[row * 64 + sb * 8];
            }
            #pragma unroll
            for (int i = 0; i < MI; ++i)
                #pragma unroll
                for (int j = 0; j < 4; ++j)
                    acc[i][j] = __builtin_amdgcn_mfma_f32_16x16x32_bf16(a[i], b[j], acc[i][j], 0, 0, 0);
        }
        __syncthreads();
    }
    float* Cfz = Cf + (size_t)zz * M * N;
    #pragma unroll
    for (int i = 0; i < MI; ++i) {
        int rowb = m0 + wr * (BM / 2) + i * 16 + fq * 4;
        #pragma unroll
        for (int j = 0; j < 4; ++j) {
            int col = n0 + wc * 64 + j * 16 + fr;
            float bv = (EPI == 3) ? 0.f : bias[col];
            #pragma unroll
            for (int t = 0; t < 4; ++t) {
                size_t idx = (size_t)(rowb + t) * N + col;
                float v = acc[i][j][t] + bv;
                if constexpr (EPI == 0) Cf[idx] = v;
                else if constexpr (EPI == 2) Cb[idx] = __float2bfloat16(v);
                else Cfz[idx] = v;
            }
        }
    }
}

// ---------------- head GEMM: n-stripe persistent-B + transposed epilogue + NT stores ----------------
// Block owns a 64-col n-stripe; B panel (64x512 = 64KB) staged once; 8 m-tiles (BM=128, BK=64).
// Grid (500,4) = 2000 blocks at 2 blocks/CU. Epilogue: rotation-swizzled wave-local LDS transpose
// -> 256B-contiguous f32x4 NONTEMPORAL stores (logits never re-read; keep them out of L2 so the
// A/B panels stay resident).
__global__ __launch_bounds__(256) void gemm_head_ns(const __hip_bfloat16* __restrict__ A,
                                                    const __hip_bfloat16* __restrict__ Bt,
                                                    const float* __restrict__ bias,
                                                    float* __restrict__ C,
                                                    int M, int N, int K) {
    __shared__ __hip_bfloat16 Bs[64 * 512];   // 64 KB persistent B panel
    __shared__ __hip_bfloat16 As[128 * 64];   // 16 KB A tile; reused as epilogue buffer
    const int tid = threadIdx.x;
    const int lane = tid & 63;
    const int wave = tid >> 6;                // 4 waves, each owns 32 rows x 64 cols
    const int n0 = blockIdx.x * 64;
    const int mbase = blockIdx.y * 1024;      // 8 m-tiles of 128
    const int fr = lane & 15, fq = lane >> 4;
    // stage B panel: slot c = (row, kc, cb); source colblk gcb = cb^(row&7)
    #pragma unroll
    for (int q = 0; q < 16; ++q) {
        int c = q * 256 + tid;
        int row = c >> 6, rem = c & 63;
        int kc = rem >> 3, cb = rem & 7;
        int gcb = cb ^ (row & 7);
        gload_lds16(Bt + (size_t)(n0 + row) * K + (kc * 64 + gcb * 8), &Bs[c * 8]);
    }
    // epilogue constants (per lane)
    float* ebuf = (float*)As + wave * 1024;   // 16 rows x 64 f32 per wave
    const int erow = lane >> 4;               // 0..3 (row group for reads)
    const int ecol = (lane & 15) * 4;         // col start (true col)
    f32x4 bias4 = *(const f32x4*)&bias[n0 + ecol];
    for (int mt = 0; mt < 8; ++mt) {
        const int m0 = mbase + mt * 128;
        f32x4 acc[2][4] = {};
        for (int kc = 0; kc < 8; ++kc) {
            if (kc == 0) __syncthreads();      // epilogue readers done before As overwrite
            #pragma unroll
            for (int q = 0; q < 4; ++q) {
                int c = q * 256 + tid;
                int row = c >> 3, cb = c & 7;
                int gcb = cb ^ (row & 7);
                gload_lds16(A + (size_t)(m0 + row) * K + (kc * 64 + gcb * 8), &As[c * 8]);
            }
            __syncthreads();   // drains staging (and B on first iter)
            #pragma unroll
            for (int ks = 0; ks < 2; ++ks) {
                short8 a[2], b[4];
                #pragma unroll
                for (int i = 0; i < 2; ++i) {
                    int row = wave * 32 + i * 16 + fr;
                    int sb = (ks * 4 + fq) ^ (row & 7);
                    a[i] = *(const short8*)&As[row * 64 + sb * 8];
                }
                #pragma unroll
                for (int j = 0; j < 4; ++j) {
                    int row = j * 16 + fr;
                    int sb = (ks * 4 + fq) ^ (row & 7);
                    b[j] = *(const short8*)&Bs[row * 512 + kc * 64 + sb * 8];
                }
                #pragma unroll
                for (int i = 0; i < 2; ++i)
                    #pragma unroll
                    for (int j = 0; j < 4; ++j)
                        acc[i][j] = __builtin_amdgcn_mfma_f32_16x16x32_bf16(a[i], b[j], acc[i][j], 0, 0, 0);
            }
            __syncthreads();   // protect As before next stage
        }
        // ---- wave-local transposed epilogue (no cross-wave sync needed) ----
        #pragma unroll
        for (int i = 0; i < 2; ++i) {
            // producer: scalar ds_write with rotation swizzle
            #pragma unroll
            for (int j = 0; j < 4; ++j)
                #pragma unroll
                for (int t = 0; t < 4; ++t) {
                    int row = fq * 4 + t;                       // 0..15 in-fragment
                    int col = j * 16 + fr;
                    ebuf[row * 64 + ((col + 4 * row) & 63)] = acc[i][j][t];
                }
            // consumer: 4 rows per pass, 256B contiguous nontemporal stores
            #pragma unroll
            for (int k = 0; k < 4; ++k) {
                int rowf = erow + 4 * k;                        // 0..15
                int colp = (ecol + 4 * rowf) & 63;
                f32x4 v = *(f32x4*)&ebuf[rowf * 64 + colp];
                f32x4 o = v + bias4;
                int grow = m0 + wave * 32 + i * 16 + rowf;
                __builtin_nontemporal_store(o, (f32x4*)&C[(size_t)grow * N + n0 + ecol]);
            }
        }
    }
}

// ---------------- scan pass 1: per-segment totals ----------------
// segTot layout: [B][NSEG][6][D]  (q: 0=P 1=cosP 2=sinP 3=Wc 4=Ws 5=Acc)
__global__ __launch_bounds__(256) void scan_pass1(const __hip_bfloat16* __restrict__ ommag,
                                                  const __hip_bfloat16* __restrict__ h16,
                                                  const float* __restrict__ iscale,
                                                  float* __restrict__ segTot) {
    int td = threadIdx.x;          // 0..63
    int ts = threadIdx.y;          // 0..3
    int d = blockIdx.x * 64 + td;
    int seg = blockIdx.y * 4 + ts;
    int b = blockIdx.z;
    size_t rbase = (size_t)b * Sc + seg * SEG;
    const __hip_bfloat16* om = ommag + rbase * 1024 + d;
    const __hip_bfloat16* mg = om + 512;
    const __hip_bfloat16* hp = h16 + rbase * Dc + d;
    float isc = fabsf(iscale[d]);
    float phi = 0.f, swc = 0.f, sws = 0.f, sacc = 0.f;
    for (int k = 0; k < SEG; ++k) {
        float o = __bfloat162float(om[(size_t)k * 1024]);
        float mp = __bfloat162float(mg[(size_t)k * 1024]);
        float hh = __bfloat162float(hp[(size_t)k * Dc]);
        phi += o * isc;
        float mag = 5.f / (1.f + __expf(-mp));
        float sn, cs; __sincosf(phi, &sn, &cs);
        float w = mag * hh;
        swc += w * cs; sws += w * sn; sacc += mag;
    }
    float cP, sP; __sincosf(phi, &sP, &cP);
    size_t o = (((size_t)b * NSEG + seg) * 6) * Dc + d;
    segTot[o] = phi; segTot[o + Dc] = cP; segTot[o + 2 * Dc] = sP;
    segTot[o + 3 * Dc] = swc; segTot[o + 4 * Dc] = sws; segTot[o + 5 * Dc] = sacc;
}

// ---------------- scan pass 3: quartered associative lookback + sweep, write ctx ----------------
__global__ __launch_bounds__(256) void scan_pass3(const __hip_bfloat16* __restrict__ ommag,
                                                  const __hip_bfloat16* __restrict__ h16,
                                                  const float* __restrict__ iscale,
                                                  const float* __restrict__ segTot,
                                                  __hip_bfloat16* __restrict__ ctx) {
    __shared__ float Q[4][6][64];   // per-quarter summary: P, zr, zi, Wr, Wi, A
    int td = threadIdx.x;
    int ts = threadIdx.y;
    int d = blockIdx.x * 64 + td;
    int jj = blockIdx.y;            // block covers segs 4jj..4jj+3
    int seg = jj * 4 + ts;
    int b = blockIdx.z;
    size_t rbase = (size_t)b * Sc + seg * SEG;
    const __hip_bfloat16* om = ommag + rbase * 1024 + d;
    const __hip_bfloat16* mg = om + 512;
    const __hip_bfloat16* hp = h16 + rbase * Dc + d;
    float isc = fabsf(iscale[d]);
    // phase A: quarter ts summarizes segments [ts*jj, (ts+1)*jj) in local frame
    {
        float Pq = 0.f, zr = 1.f, zi = 0.f, Wr = 0.f, Wi = 0.f, Aq = 0.f;
        for (int c = ts * jj; c < (ts + 1) * jj; ++c) {
            size_t o = (((size_t)b * NSEG + c) * 6) * Dc + d;
            float P = segTot[o], cp = segTot[o + Dc], sp = segTot[o + 2 * Dc];
            float wcv = segTot[o + 3 * Dc], wsv = segTot[o + 4 * Dc], acv = segTot[o + 5 * Dc];
            Wr += zr * wcv - zi * wsv;
            Wi += zi * wcv + zr * wsv;
            Aq += acv; Pq += P;
            float nzr = zr * cp - zi * sp;
            float nzi = zi * cp + zr * sp;
            zr = nzr; zi = nzi;
        }
        Q[ts][0][td] = Pq; Q[ts][1][td] = zr; Q[ts][2][td] = zi;
        Q[ts][3][td] = Wr; Q[ts][4][td] = Wi; Q[ts][5][td] = Aq;
    }
    __syncthreads();
    // phase B: compose quarters 0..3 (prefix [0,4jj)), then singles [4jj, 4jj+ts)
    float PHI = 0.f, UR = 0.f, UI = 0.f, AC = 0.f, gzr = 1.f, gzi = 0.f;
    #pragma unroll
    for (int q = 0; q < 4; ++q) {
        float wr = Q[q][3][td], wi = Q[q][4][td];
        UR += gzr * wr - gzi * wi;
        UI += gzi * wr + gzr * wi;
        AC += Q[q][5][td]; PHI += Q[q][0][td];
        float nzr = gzr * Q[q][1][td] - gzi * Q[q][2][td];
        float nzi = gzi * Q[q][1][td] + gzr * Q[q][2][td];
        gzr = nzr; gzi = nzi;
    }
    for (int c = 4 * jj; c < 4 * jj + ts; ++c) {
        size_t o = (((size_t)b * NSEG + c) * 6) * Dc + d;
        float P = segTot[o], cp = segTot[o + Dc], sp = segTot[o + 2 * Dc];
        float wcv = segTot[o + 3 * Dc], wsv = segTot[o + 4 * Dc], acv = segTot[o + 5 * Dc];
        UR += gzr * wcv - gzi * wsv;
        UI += gzi * wcv + gzr * wsv;
        AC += acv; PHI += P;
        float nzr = gzr * cp - gzi * sp;
        float nzi = gzi * cp + gzr * sp;
        gzr = nzr; gzi = nzi;
    }
    // phase C: sweep, write ctx
    float phi = PHI;
    __hip_bfloat16* ctxp = ctx + rbase * (4 * Dc) + d;
    for (int k = 0; k < SEG; ++k) {
        float o = __bfloat162float(om[(size_t)k * 1024]);
        float mp = __bfloat162float(mg[(size_t)k * 1024]);
        float hh = __bfloat162float(hp[(size_t)k * Dc]);
        phi += o * isc;
        float mag = 5.f / (1.f + __expf(-mp));
        float sn, cs; __sincosf(phi, &sn, &cs);
        float w = mag * hh;
        UR += w * cs; UI += w * sn; AC += mag;
        float inv = 1.f / (AC + 1e-8f);
        float mr = UR * inv, mi = UI * inv;
        float rr = mr * cs + mi * sn;
        float ri = mi * cs - mr * sn;
        size_t oo = (size_t)k * (4 * Dc);
        ctxp[oo]          = __float2bfloat16(hh * cs);
        ctxp[oo + Dc]     = __float2bfloat16(hh * sn);
        ctxp[oo + 2 * Dc] = __float2bfloat16(rr);
        ctxp[oo + 3 * Dc] = __float2bfloat16(ri);
    }
}

// ---------------- launch ----------------
extern "C" void kernel_launch(void* const* d_in, const int* in_sizes, int n_in,
                              void* d_out, int out_size, void* d_ws, size_t ws_size,
                              hipStream_t stream) {
    const int*   tokens    = (const int*)d_in[0];
    const float* emb       = (const float*)d_in[1];
    const float* ln_w      = (const float*)d_in[2];
    const float* ln_b      = (const float*)d_in[3];
    const float* W_omega   = (const float*)d_in[4];
    const float* b_omega   = (const float*)d_in[5];
    const float* int_scale = (const float*)d_in[6];
    const float* W_mag     = (const float*)d_in[7];
    const float* b_mag     = (const float*)d_in[8];
    const float* W_out     = (const float*)d_in[9];
    const float* b_out     = (const float*)d_in[10];
    const float* fln_w     = (const float*)d_in[11];
    const float* fln_b     = (const float*)d_in[12];
    const float* W_head    = (const float*)d_in[13];
    const float* b_head    = (const float*)d_in[14];
    float* out = (float*)d_out;

    char* ws = (char*)d_ws;
    size_t off = 0;
    auto alloc = [&](size_t bytes) -> char* {
        char* p = ws + off;
        off += (bytes + 255) / 256 * 256;
        return p;
    };
    const size_t MD = (size_t)Mc * Dc;
    float* x        = (float*)alloc(MD * 4);
    float* part     = (float*)alloc(MD * 4 * 4);                    // split-K partials [4][M][512]
    __hip_bfloat16* ommag16 = (__hip_bfloat16*)alloc(MD * 2 * 2);   // [M][1024] bf16
    __hip_bfloat16* h16    = (__hip_bfloat16*)alloc(MD * 2);
    __hip_bfloat16* ctx16  = (__hip_bfloat16*)alloc(MD * 4 * 2);
    __hip_bfloat16* xln16  = (__hip_bfloat16*)alloc(MD * 2);
    float* segTot   = (float*)alloc((size_t)Bc * NSEG * 6 * Dc * 4);
    __hip_bfloat16* Wt_ommag = (__hip_bfloat16*)alloc((size_t)Lc * 1024 * Dc * 2);
    __hip_bfloat16* Wt_out   = (__hip_bfloat16*)alloc((size_t)Lc * Dc * 4 * Dc * 2);
    __hip_bfloat16* Wt_head  = (__hip_bfloat16*)alloc((size_t)Vc * Dc * 2);
    float* bias_ommag        = (float*)alloc((size_t)Lc * 1024 * 4);

    // fused prep: embed+LN0 + all transposes + bias pack (26244 blocks)
    prep_all<<<26244, dim3(32, 8), 0, stream>>>(
        tokens, emb, ln_w, ln_b, x, h16,
        W_omega, W_mag, W_out, W_head, b_omega, b_mag,
        Wt_ommag, Wt_out, Wt_head, bias_ommag);

    dim3 scanGrid(Dc / 64, NSEG / 4, Bc);
    dim3 scanBlk(64, 4);
    for (int l = 0; l < Lc; ++l) {
        gemm_bt<128, 2><<<dim3(1024 / 128, Mc / 128), 256, 0, stream>>>(
            h16, Wt_ommag + (size_t)l * 1024 * Dc, bias_ommag + l * 1024, nullptr, ommag16, Mc, 1024, Dc);
        scan_pass1<<<scanGrid, scanBlk, 0, stream>>>(ommag16, h16, int_scale + l * Dc, segTot);
        scan_pass3<<<scanGrid, scanBlk, 0, stream>>>(ommag16, h16, int_scale + l * Dc, segTot, ctx16);
        gemm_bt<128, 3, 4><<<dim3(Dc / 128, Mc / 128, 4), 256, 0, stream>>>(
            ctx16, Wt_out + (size_t)l * Dc * 4 * Dc, nullptr, part, nullptr, Mc, Dc, 4 * Dc);
        const float* wsel = (l + 1 < Lc) ? (ln_w + (l + 1) * Dc) : fln_w;
        const float* bsel = (l + 1 < Lc) ? (ln_b + (l + 1) * Dc) : fln_b;
        __hip_bfloat16* hsel = (l + 1 < Lc) ? h16 : xln16;
        reduce_ln<<<Mc, 256, 0, stream>>>(part, b_out + l * Dc, x, h16, wsel, bsel, hsel,
                                          (l + 1 < Lc) ? 1 : 0);
    }
    // head: n-stripe persistent-B, 8 m-tiles per block, NT logit stores
    gemm_head_ns<<<dim3(Vc / 64, Mc / 1024), 256, 0, stream>>>(
        xln16, Wt_head, b_head, out, Mc, Vc, Dc);
}